// Round 1
// baseline (1627.765 us; speedup 1.0000x reference)
//
#include <hip/hip_runtime.h>
#include <hip/hip_bf16.h>

#define S_LEN 2048
#define EMB   512
#define NH    8
#define DH    64
#define NB    4

#define TQ 32
#define TK 32
#define DP 68   // padded row stride (68*4=272 bytes, multiple of 16 -> float4 aligned)

__device__ __forceinline__ float dot4(const float4 a, const float4 b) {
    return a.x*b.x + a.y*b.y + a.z*b.z + a.w*b.w;
}

// ---------------- Kernel 1: q/k/v projections ----------------
// one block per token; 256 threads; each thread computes 2 (h,dd) outputs per matrix
__global__ __launch_bounds__(256) void qkv_kernel(
    const float* __restrict__ x,
    const float* __restrict__ Wq, const float* __restrict__ bq,
    const float* __restrict__ Wk, const float* __restrict__ bk,
    const float* __restrict__ Wv, const float* __restrict__ bv,
    float* __restrict__ q, float* __restrict__ k, float* __restrict__ v)
{
    __shared__ float xr[EMB];
    const int t = blockIdx.x;               // token index 0..N*S-1
    const int n = t / S_LEN, s = t % S_LEN;
    const float* xrow = x + (size_t)t * EMB;
    for (int i = threadIdx.x; i < EMB; i += 256) xr[i] = xrow[i];
    __syncthreads();

    for (int p = threadIdx.x; p < EMB; p += 256) {
        const int h = p >> 6, dd = p & 63;
        const float4* xh4 = (const float4*)(&xr[h * 64]);
        const float4* wq4 = (const float4*)(Wq + dd * 64);
        const float4* wk4 = (const float4*)(Wk + dd * 64);
        const float4* wv4 = (const float4*)(Wv + dd * 64);
        float aq = bq[dd], ak = bk[dd], av = bv[dd];
        #pragma unroll
        for (int d4 = 0; d4 < 16; ++d4) {
            float4 xv = xh4[d4];
            aq += dot4(xv, wq4[d4]);
            ak += dot4(xv, wk4[d4]);
            av += dot4(xv, wv4[d4]);
        }
        const size_t base = (((size_t)(n*NH + h))*S_LEN + s)*DH + dd;
        q[base] = aq; k[base] = ak; v[base] = av;
    }
}

// ---------------- Kernel 2: fused attention ----------------
// attention[q,k] = softmax_{k>q}(qk/sqrt(512)) + [k<=q] * (q . E[S-1-(q-k)])
// row q=S-1: softmax part is uniform 1/S over ALL k.
// z = attention @ v   -> z buffer [N][S][EMB]
__global__ __launch_bounds__(256) void attn_kernel(
    const float* __restrict__ qg, const float* __restrict__ kg,
    const float* __restrict__ vg, const float* __restrict__ Eg,
    float* __restrict__ z)
{
    __shared__ float q_lds[TQ][DP];
    __shared__ float k_lds[TK][DP];
    __shared__ float v_lds[TK][DP];
    __shared__ float e_lds[2*TK - 1][DP];
    __shared__ float ws_t[TQ][TK + 1];
    __shared__ float wr_t[TQ][TK + 1];
    __shared__ float denom[TQ];

    constexpr float SM_SCALE = 0.04419417382415922f; // 1/sqrt(512)
    const int nqt = S_LEN / TQ;
    const int bid = blockIdx.x;
    const int qt = bid % nqt;
    const int h  = (bid / nqt) % NH;
    const int n  = bid / (nqt * NH);
    const int q0 = qt * TQ;
    const size_t base = ((size_t)(n*NH + h)) * S_LEN * DH;
    const float* qp = qg + base;
    const float* kp = kg + base;
    const float* vp = vg + base;

    const int tid = threadIdx.x;

    for (int i = tid; i < TQ*DH; i += 256) {
        int r = i >> 6, d = i & 63;
        q_lds[r][d] = qp[(size_t)(q0 + r)*DH + d];
    }
    if (tid < TQ) denom[tid] = 0.f;

    // compute-phase mapping: row qq, 4 consecutive kk per thread
    const int qq  = tid >> 3;
    const int kk0 = (tid & 7) * 4;
    const int qrow = q0 + qq;
    const bool lastrow = (qrow == S_LEN - 1);
    // accumulate-phase mapping: row qq, 8 consecutive dims per thread
    const int da0 = (tid & 7) * 8;

    float accS[8], accR[8];
    #pragma unroll
    for (int j = 0; j < 8; ++j) { accS[j] = 0.f; accR[j] = 0.f; }

    for (int k0 = 0; k0 < S_LEN; k0 += TK) {
        __syncthreads();   // protects LDS reuse; also covers initial q staging
        for (int i = tid; i < TK*DH; i += 256) {
            int r = i >> 6, d = i & 63;
            k_lds[r][d] = kp[(size_t)(k0 + r)*DH + d];
            v_lds[r][d] = vp[(size_t)(k0 + r)*DH + d];
        }
        // stage E rows for delta = q-k in [ds, de]; Ehat[delta] = E[S-1-delta]
        const int de = q0 + TQ - 1 - k0;
        int ds = q0 - k0 - (TK - 1); if (ds < 0) ds = 0;
        if (de >= 0) {
            const int rows = de - ds + 1;
            for (int i = tid; i < rows*DH; i += 256) {
                int r = i >> 6, d = i & 63;
                e_lds[r][d] = Eg[(size_t)(S_LEN - 1 - (ds + r))*DH + d];
            }
        }
        __syncthreads();

        float psum = 0.f;
        #pragma unroll
        for (int kx = 0; kx < 4; ++kx) {
            const int kk = kk0 + kx;
            const int krow = k0 + kk;
            float wS = 0.f, wR = 0.f;
            if (lastrow) {
                wS = 1.0f;                       // uniform softmax row
            } else if (krow > qrow) {
                float s = 0.f;
                const float4* qv = (const float4*)q_lds[qq];
                const float4* kv = (const float4*)k_lds[kk];
                #pragma unroll
                for (int d4 = 0; d4 < 16; ++d4) s += dot4(qv[d4], kv[d4]);
                wS = __expf(s * SM_SCALE);
            }
            if (krow <= qrow) {
                const int dl = qrow - krow - ds;
                float r = 0.f;
                const float4* qv = (const float4*)q_lds[qq];
                const float4* ev = (const float4*)e_lds[dl];
                #pragma unroll
                for (int d4 = 0; d4 < 16; ++d4) r += dot4(qv[d4], ev[d4]);
                wR = r;
            }
            ws_t[qq][kk] = wS;
            wr_t[qq][kk] = wR;
            psum += wS;
        }
        // reduce softmax partial within the 8-thread group owning row qq
        psum += __shfl_down(psum, 4, 8);
        psum += __shfl_down(psum, 2, 8);
        psum += __shfl_down(psum, 1, 8);
        if ((tid & 7) == 0) denom[qq] += psum;
        __syncthreads();

        #pragma unroll 8
        for (int kk = 0; kk < TK; ++kk) {
            const float wS = ws_t[qq][kk];
            const float wR = wr_t[qq][kk];
            const float4* vv = (const float4*)&v_lds[kk][da0];
            const float4 v0 = vv[0], v1 = vv[1];
            accS[0] += wS*v0.x; accS[1] += wS*v0.y; accS[2] += wS*v0.z; accS[3] += wS*v0.w;
            accS[4] += wS*v1.x; accS[5] += wS*v1.y; accS[6] += wS*v1.z; accS[7] += wS*v1.w;
            accR[0] += wR*v0.x; accR[1] += wR*v0.y; accR[2] += wR*v0.z; accR[3] += wR*v0.w;
            accR[4] += wR*v1.x; accR[5] += wR*v1.y; accR[6] += wR*v1.z; accR[7] += wR*v1.w;
        }
    }

    const float inv = 1.0f / denom[qq];
    const size_t zb = ((size_t)n * S_LEN + qrow) * EMB + h * DH + da0;
    #pragma unroll
    for (int j = 0; j < 8; ++j) z[zb + j] = accS[j]*inv + accR[j];
}

// ---------------- Kernel 3: output projection ----------------
// out[t][o] = sum_e z[t][e] * Wo[o][e] + bo[o]
#define TT 32
#define TO 64
#define TE 32
__global__ __launch_bounds__(256) void outproj_kernel(
    const float* __restrict__ z, const float* __restrict__ Wo,
    const float* __restrict__ bo, float* __restrict__ out)
{
    __shared__ float z_t[TT][TE + 1];
    __shared__ float w_t[TE][TO + 4];

    const int ntt = (NB * S_LEN) / TT;
    const int tb = blockIdx.x % ntt;
    const int ob = blockIdx.x / ntt;
    const int t0 = tb * TT, o0 = ob * TO;
    const int tid = threadIdx.x;
    const int tt = tid >> 3, oo0 = (tid & 7) * 8;

    float acc[8];
    #pragma unroll
    for (int j = 0; j < 8; ++j) acc[j] = 0.f;

    for (int e0 = 0; e0 < EMB; e0 += TE) {
        __syncthreads();
        for (int i = tid; i < TT*TE; i += 256) {
            int r = i >> 5, c = i & 31;
            z_t[r][c] = z[(size_t)(t0 + r)*EMB + e0 + c];
        }
        for (int i = tid; i < TO*TE; i += 256) {
            int oo = i >> 5, ee = i & 31;
            w_t[ee][oo] = Wo[(size_t)(o0 + oo)*EMB + e0 + ee];
        }
        __syncthreads();
        #pragma unroll 8
        for (int ee = 0; ee < TE; ++ee) {
            const float zv = z_t[tt][ee];
            const float4* wv = (const float4*)&w_t[ee][oo0];
            const float4 w0 = wv[0], w1 = wv[1];
            acc[0] += zv*w0.x; acc[1] += zv*w0.y; acc[2] += zv*w0.z; acc[3] += zv*w0.w;
            acc[4] += zv*w1.x; acc[5] += zv*w1.y; acc[6] += zv*w1.z; acc[7] += zv*w1.w;
        }
    }
    const size_t obase = (size_t)(t0 + tt)*EMB + o0 + oo0;
    #pragma unroll
    for (int j = 0; j < 8; ++j) out[obase + j] = acc[j] + bo[o0 + oo0 + j];
}

// ---------------- launch ----------------
extern "C" void kernel_launch(void* const* d_in, const int* in_sizes, int n_in,
                              void* d_out, int out_size, void* d_ws, size_t ws_size,
                              hipStream_t stream) {
    const float* x  = (const float*)d_in[0];
    const float* Wq = (const float*)d_in[1];
    const float* bq = (const float*)d_in[2];
    const float* Wk = (const float*)d_in[3];
    const float* bk = (const float*)d_in[4];
    const float* Wv = (const float*)d_in[5];
    const float* bv = (const float*)d_in[6];
    const float* E  = (const float*)d_in[7];
    const float* Wo = (const float*)d_in[8];
    const float* bo = (const float*)d_in[9];
    float* out = (float*)d_out;

    const size_t per = (size_t)NB * NH * S_LEN * DH;   // 4M floats
    float* qbuf = (float*)d_ws;
    float* kbuf = qbuf + per;
    float* vbuf = kbuf + per;
    float* zbuf = vbuf + per;                          // N*S*EMB = 4M floats

    qkv_kernel<<<NB * S_LEN, 256, 0, stream>>>(x, Wq, bq, Wk, bk, Wv, bv,
                                               qbuf, kbuf, vbuf);
    attn_kernel<<<NB * NH * (S_LEN / TQ), 256, 0, stream>>>(qbuf, kbuf, vbuf, E, zbuf);
    outproj_kernel<<<(NB * S_LEN / TT) * (EMB / TO), 256, 0, stream>>>(zbuf, Wo, bo, out);
}

// Round 2
// 430.043 us; speedup vs baseline: 3.7851x; 3.7851x over previous
//
#include <hip/hip_runtime.h>
#include <hip/hip_bf16.h>

#define S_LEN 2048
#define EMB   512
#define NH    8
#define DH    64
#define NB    4

typedef float f32x4  __attribute__((ext_vector_type(4)));
typedef short short8 __attribute__((ext_vector_type(8)));

__device__ __forceinline__ unsigned short f2bf(float f) {
    unsigned u = __builtin_bit_cast(unsigned, f);
    u += 0x7fffu + ((u >> 16) & 1u);
    return (unsigned short)(u >> 16);
}

__device__ __forceinline__ f32x4 mfma16(short8 a, short8 b, f32x4 c) {
    return __builtin_amdgcn_mfma_f32_16x16x32_bf16(a, b, c, 0, 0, 0);
}

__device__ __forceinline__ float dot4(const float4 a, const float4 b) {
    return a.x*b.x + a.y*b.y + a.z*b.z + a.w*b.w;
}

// stage a 64x64 bf16 tile into LDS with XOR-swizzle (T2): byte ^= ((row&7)<<4)
__device__ __forceinline__ void stage_tile(const unsigned short* __restrict__ g,
                                           int gstride, unsigned short* lds, int tid)
{
    #pragma unroll
    for (int c = tid; c < 512; c += 256) {
        const int r = c >> 3, s = c & 7;
        short8 v = *reinterpret_cast<const short8*>(g + (size_t)r * gstride + s * 8);
        char* dst = (char*)lds + r * 128 + ((s * 16) ^ ((r & 7) << 4));
        *reinterpret_cast<short8*>(dst) = v;
    }
}

// read one MFMA A/B fragment octet (8 bf16) from a swizzled 64x64 tile
__device__ __forceinline__ short8 frag_read(const unsigned short* lds, int row, int oct)
{
    const char* src = (const char*)lds + row * 128 + ((oct * 16) ^ ((row & 7) << 4));
    return *reinterpret_cast<const short8*>(src);
}

// ---------------- Kernel 1: q/k/v projections (bf16 out) ----------------
__global__ __launch_bounds__(256) void qkv_kernel(
    const float* __restrict__ x,
    const float* __restrict__ Wq, const float* __restrict__ bq,
    const float* __restrict__ Wk, const float* __restrict__ bk,
    const float* __restrict__ Wv, const float* __restrict__ bv,
    unsigned short* __restrict__ q, unsigned short* __restrict__ k,
    unsigned short* __restrict__ v)
{
    __shared__ float xr[EMB];
    const int t = blockIdx.x;
    const int n = t / S_LEN, s = t % S_LEN;
    const float* xrow = x + (size_t)t * EMB;
    for (int i = threadIdx.x; i < EMB; i += 256) xr[i] = xrow[i];
    __syncthreads();

    for (int p = threadIdx.x; p < EMB; p += 256) {
        const int h = p >> 6, dd = p & 63;
        const float4* xh4 = (const float4*)(&xr[h * 64]);
        const float4* wq4 = (const float4*)(Wq + dd * 64);
        const float4* wk4 = (const float4*)(Wk + dd * 64);
        const float4* wv4 = (const float4*)(Wv + dd * 64);
        float aq = bq[dd], ak = bk[dd], av = bv[dd];
        #pragma unroll
        for (int d4 = 0; d4 < 16; ++d4) {
            float4 xv = xh4[d4];
            aq += dot4(xv, wq4[d4]);
            ak += dot4(xv, wk4[d4]);
            av += dot4(xv, wv4[d4]);
        }
        const size_t base = (((size_t)(n*NH + h))*S_LEN + s)*DH + dd;
        q[base] = f2bf(aq); k[base] = f2bf(ak); v[base] = f2bf(av);
    }
}

// ---------------- Kernel 1b: transpose V -> vT [nh][64][S] ----------------
__global__ __launch_bounds__(256) void transpose_v(
    const unsigned short* __restrict__ v, unsigned short* __restrict__ vt)
{
    __shared__ unsigned short t_lds[64][72];
    const int bid = blockIdx.x;
    const int st = bid % (S_LEN / 64);
    const int nh = bid / (S_LEN / 64);
    const unsigned short* vp = v + ((size_t)nh * S_LEN + st * 64) * DH;
    unsigned short* vtp = vt + (size_t)nh * DH * S_LEN + st * 64;
    const int tid = threadIdx.x;
    #pragma unroll
    for (int c = tid; c < 512; c += 256) {
        const int r = c >> 3, s = c & 7;
        short8 xv = *reinterpret_cast<const short8*>(vp + r * DH + s * 8);
        #pragma unroll
        for (int i = 0; i < 8; ++i) t_lds[s * 8 + i][r] = (unsigned short)xv[i];
    }
    __syncthreads();
    #pragma unroll
    for (int c = tid; c < 512; c += 256) {
        const int d = c >> 3, s = c & 7;
        short8 y;
        #pragma unroll
        for (int i = 0; i < 8; ++i) y[i] = (short)t_lds[d][s * 8 + i];
        *reinterpret_cast<short8*>(vtp + (size_t)d * S_LEN + s * 8) = y;
    }
}

// ---------------- Kernel 1c: Ehat bf16, reversed rows ----------------
__global__ __launch_bounds__(256) void prep_e(
    const float* __restrict__ E, unsigned short* __restrict__ eb)
{
    const int i = blockIdx.x * 256 + threadIdx.x;
    if (i >= S_LEN * DH) return;
    const int dlt = i >> 6, d = i & 63;
    eb[i] = f2bf(E[(size_t)(S_LEN - 1 - dlt) * DH + d]);
}

// ---------------- Kernel 2: fused MFMA attention ----------------
__global__ __launch_bounds__(256) void attn_mfma(
    const unsigned short* __restrict__ qg,
    const unsigned short* __restrict__ kg,
    const unsigned short* __restrict__ vtg,
    const unsigned short* __restrict__ eg,
    float* __restrict__ z)
{
    __shared__ unsigned short k_lds[64 * 64];
    __shared__ unsigned short vT_lds[64 * 64];
    __shared__ unsigned short e_lds[64 * 64];
    __shared__ unsigned short p_lds[2][64 * 64];

    constexpr float SM_SCALE = 0.04419417382415922f; // 1/sqrt(512)
    constexpr float UNI = 1.0f / 2048.0f;

    const int nqt = S_LEN / 64;
    const int bid = blockIdx.x;
    const int qt = bid % nqt;
    const int nh = bid / nqt;            // n*NH + h
    const int q0 = qt * 64;
    const size_t base = (size_t)nh * S_LEN * DH;
    const unsigned short* qp = qg + base;
    const unsigned short* kp = kg + base;
    const unsigned short* vp = vtg + base;   // [64][S]

    const int tid  = threadIdx.x;
    const int lane = tid & 63;
    const int w    = tid >> 6;
    const int rowg = lane & 15;
    const int og   = lane >> 4;

    // Q A-fragments for this wave's 16-row stripe (rows q0+16w .. +16)
    short8 qa0, qa1;
    {
        const unsigned short* qr = qp + (size_t)(q0 + 16 * w + rowg) * DH + og * 8;
        qa0 = *reinterpret_cast<const short8*>(qr);
        qa1 = *reinterpret_cast<const short8*>(qr + 32);
    }

    const f32x4 zero4 = {0.f, 0.f, 0.f, 0.f};
    f32x4 accS[4], accR[4];
    #pragma unroll
    for (int t = 0; t < 4; ++t) { accS[t] = zero4; accR[t] = zero4; }
    float denom[4] = {0.f, 0.f, 0.f, 0.f};
    const int qrow0 = q0 + 16 * w + og * 4;   // C-layout row for reg 0

    // ================= Phase A: softmax part (k > q) =================
    for (int k0 = q0; k0 < S_LEN; k0 += 64) {
        __syncthreads();
        stage_tile(kp + (size_t)k0 * DH, DH, k_lds, tid);
        stage_tile(vp + k0, S_LEN, vT_lds, tid);
        __syncthreads();

        f32x4 P[4];
        #pragma unroll
        for (int t = 0; t < 4; ++t) {
            f32x4 c = zero4;
            c = mfma16(qa0, frag_read(k_lds, 16 * t + rowg, og),     c);
            c = mfma16(qa1, frag_read(k_lds, 16 * t + rowg, og + 4), c);
            P[t] = c;
        }

        float rsum[4] = {0.f, 0.f, 0.f, 0.f};
        #pragma unroll
        for (int t = 0; t < 4; ++t) {
            const int kcol = k0 + 16 * t + rowg;
            #pragma unroll
            for (int r = 0; r < 4; ++r) {
                const int qrow = qrow0 + r;
                float wv = 0.f;
                if (kcol > qrow && qrow != S_LEN - 1)
                    wv = __expf(P[t][r] * SM_SCALE);
                rsum[r] += wv;
                const int prow = 16 * w + og * 4 + r;
                const int pcol = 16 * t + rowg;
                char* dst = (char*)p_lds[0] + prow * 128 + ((pcol * 2) ^ ((prow & 7) << 4));
                *reinterpret_cast<unsigned short*>(dst) = f2bf(wv);
            }
        }
        #pragma unroll
        for (int r = 0; r < 4; ++r) {
            float vv = rsum[r];
            vv += __shfl_xor(vv, 1, 16);
            vv += __shfl_xor(vv, 2, 16);
            vv += __shfl_xor(vv, 4, 16);
            vv += __shfl_xor(vv, 8, 16);
            denom[r] += vv;
        }

        const short8 pa0 = frag_read(p_lds[0], 16 * w + rowg, og);
        const short8 pa1 = frag_read(p_lds[0], 16 * w + rowg, og + 4);
        #pragma unroll
        for (int t = 0; t < 4; ++t) {
            accS[t] = mfma16(pa0, frag_read(vT_lds, 16 * t + rowg, og),     accS[t]);
            accS[t] = mfma16(pa1, frag_read(vT_lds, 16 * t + rowg, og + 4), accS[t]);
        }
    }

    // zero this wave's stripe of p_lds[0] (phase B j=0 needs kk>qq == 0)
    {
        const short8 z8 = {0, 0, 0, 0, 0, 0, 0, 0};
        #pragma unroll
        for (int c2 = lane; c2 < 128; c2 += 64) {
            const int r = 16 * w + (c2 >> 3), s = c2 & 7;
            *reinterpret_cast<short8*>((char*)p_lds[0] + r * 128 + s * 16) = z8;
        }
    }

    // ============ Phase B: relative-position part (k <= q) ============
    // G[qq][c] = Q[qq] . Ehat[64j + c]; wR[qq][kk] = G[qq][qq-kk+64j]
    const int jmax = q0 / 64;
    for (int j = 0; j <= jmax; ++j) {
        const int k0 = q0 - 64 * j;
        __syncthreads();
        stage_tile(eg + (size_t)(64 * j) * DH, DH, e_lds, tid);
        stage_tile(vp + k0, S_LEN, vT_lds, tid);
        __syncthreads();

        f32x4 G[4];
        #pragma unroll
        for (int t = 0; t < 4; ++t) {
            f32x4 c = zero4;
            c = mfma16(qa0, frag_read(e_lds, 16 * t + rowg, og),     c);
            c = mfma16(qa1, frag_read(e_lds, 16 * t + rowg, og + 4), c);
            G[t] = c;
        }

        unsigned short* pc = p_lds[j & 1];
        unsigned short* pn = p_lds[(j + 1) & 1];
        #pragma unroll
        for (int t = 0; t < 4; ++t) {
            const int c = 16 * t + rowg;          // delta offset within block
            #pragma unroll
            for (int r = 0; r < 4; ++r) {
                const int qq = 16 * w + og * 4 + r;
                const int qrow = q0 + qq;
                float val = G[t][r];
                if (qrow == S_LEN - 1) val += UNI;   // uniform-softmax row fold-in
                const unsigned short bv = f2bf(val);
                if (c <= qq) {
                    const int pcol = qq - c;
                    char* dst = (char*)pc + qq * 128 + ((pcol * 2) ^ ((qq & 7) << 4));
                    *reinterpret_cast<unsigned short*>(dst) = bv;
                } else if (j < jmax) {
                    const int pcol = qq - c + 64;
                    char* dst = (char*)pn + qq * 128 + ((pcol * 2) ^ ((qq & 7) << 4));
                    *reinterpret_cast<unsigned short*>(dst) = bv;
                }
            }
        }

        const short8 pa0 = frag_read(pc, 16 * w + rowg, og);
        const short8 pa1 = frag_read(pc, 16 * w + rowg, og + 4);
        #pragma unroll
        for (int t = 0; t < 4; ++t) {
            accR[t] = mfma16(pa0, frag_read(vT_lds, 16 * t + rowg, og),     accR[t]);
            accR[t] = mfma16(pa1, frag_read(vT_lds, 16 * t + rowg, og + 4), accR[t]);
        }
    }

    // ================= epilogue: z = accS/denom + accR =================
    const int n = nh / NH, h = nh % NH;
    #pragma unroll
    for (int r = 0; r < 4; ++r) {
        const int qrow = qrow0 + r;
        const float inv = (qrow == S_LEN - 1) ? 0.f : 1.f / denom[r];
        #pragma unroll
        for (int t = 0; t < 4; ++t) {
            const float zv = accS[t][r] * inv + accR[t][r];
            z[((size_t)n * S_LEN + qrow) * EMB + h * DH + 16 * t + rowg] = zv;
        }
    }
}

// ---------------- Kernel 3: output projection ----------------
#define TT 32
#define TO 64
#define TE 32
__global__ __launch_bounds__(256) void outproj_kernel(
    const float* __restrict__ z, const float* __restrict__ Wo,
    const float* __restrict__ bo, float* __restrict__ out)
{
    __shared__ float z_t[TT][TE + 1];
    __shared__ float w_t[TE][TO + 4];

    const int ntt = (NB * S_LEN) / TT;
    const int tb = blockIdx.x % ntt;
    const int ob = blockIdx.x / ntt;
    const int t0 = tb * TT, o0 = ob * TO;
    const int tid = threadIdx.x;
    const int tt = tid >> 3, oo0 = (tid & 7) * 8;

    float acc[8];
    #pragma unroll
    for (int j = 0; j < 8; ++j) acc[j] = 0.f;

    for (int e0 = 0; e0 < EMB; e0 += TE) {
        __syncthreads();
        for (int i = tid; i < TT*TE; i += 256) {
            int r = i >> 5, c = i & 31;
            z_t[r][c] = z[(size_t)(t0 + r)*EMB + e0 + c];
        }
        for (int i = tid; i < TO*TE; i += 256) {
            int oo = i >> 5, ee = i & 31;
            w_t[ee][oo] = Wo[(size_t)(o0 + oo)*EMB + e0 + ee];
        }
        __syncthreads();
        #pragma unroll 8
        for (int ee = 0; ee < TE; ++ee) {
            const float zv = z_t[tt][ee];
            const float4* wv = (const float4*)&w_t[ee][oo0];
            const float4 w0 = wv[0], w1 = wv[1];
            acc[0] += zv*w0.x; acc[1] += zv*w0.y; acc[2] += zv*w0.z; acc[3] += zv*w0.w;
            acc[4] += zv*w1.x; acc[5] += zv*w1.y; acc[6] += zv*w1.z; acc[7] += zv*w1.w;
        }
    }
    const size_t obase = (size_t)(t0 + tt)*EMB + o0 + oo0;
    #pragma unroll
    for (int j = 0; j < 8; ++j) out[obase + j] = acc[j] + bo[o0 + oo0 + j];
}

// ---------------- launch ----------------
extern "C" void kernel_launch(void* const* d_in, const int* in_sizes, int n_in,
                              void* d_out, int out_size, void* d_ws, size_t ws_size,
                              hipStream_t stream) {
    const float* x  = (const float*)d_in[0];
    const float* Wq = (const float*)d_in[1];
    const float* bq = (const float*)d_in[2];
    const float* Wk = (const float*)d_in[3];
    const float* bk = (const float*)d_in[4];
    const float* Wv = (const float*)d_in[5];
    const float* bv = (const float*)d_in[6];
    const float* E  = (const float*)d_in[7];
    const float* Wo = (const float*)d_in[8];
    const float* bo = (const float*)d_in[9];
    float* out = (float*)d_out;

    const size_t per = (size_t)NB * NH * S_LEN * DH;       // 4M elements
    unsigned short* qb  = (unsigned short*)d_ws;
    unsigned short* kb  = qb  + per;
    unsigned short* vb  = kb  + per;
    unsigned short* vtb = vb  + per;
    unsigned short* eb  = vtb + per;
    float* zb = (float*)(eb + (size_t)S_LEN * DH);

    qkv_kernel<<<NB * S_LEN, 256, 0, stream>>>(x, Wq, bq, Wk, bk, Wv, bv, qb, kb, vb);
    transpose_v<<<NB * NH * (S_LEN / 64), 256, 0, stream>>>(vb, vtb);
    prep_e<<<(S_LEN * DH + 255) / 256, 256, 0, stream>>>(E, eb);
    attn_mfma<<<NB * NH * (S_LEN / 64), 256, 0, stream>>>(qb, kb, vtb, eb, zb);
    outproj_kernel<<<(NB * S_LEN / TT) * (EMB / TO), 256, 0, stream>>>(zb, Wo, bo, out);
}

// Round 3
// 161.890 us; speedup vs baseline: 10.0548x; 2.6564x over previous
//
#include <hip/hip_runtime.h>
#include <hip/hip_bf16.h>

#define S_LEN 2048
#define EMB   512
#define NH    8
#define DH    64
#define NB    4

typedef float f32x4  __attribute__((ext_vector_type(4)));
typedef short short8 __attribute__((ext_vector_type(8)));

__device__ __forceinline__ unsigned short f2bf(float f) {
    unsigned u = __builtin_bit_cast(unsigned, f);
    u += 0x7fffu + ((u >> 16) & 1u);
    return (unsigned short)(u >> 16);
}

__device__ __forceinline__ f32x4 mfma16(short8 a, short8 b, f32x4 c) {
    return __builtin_amdgcn_mfma_f32_16x16x32_bf16(a, b, c, 0, 0, 0);
}

// stage a 64x64 bf16 tile into LDS with XOR-swizzle (T2): byte ^= ((row&7)<<4)
__device__ __forceinline__ void stage_tile(const unsigned short* __restrict__ g,
                                           int gstride, unsigned short* lds, int tid)
{
    #pragma unroll
    for (int c = tid; c < 512; c += 256) {
        const int r = c >> 3, s = c & 7;
        short8 v = *reinterpret_cast<const short8*>(g + (size_t)r * gstride + s * 8);
        char* dst = (char*)lds + r * 128 + ((s * 16) ^ ((r & 7) << 4));
        *reinterpret_cast<short8*>(dst) = v;
    }
}

// stage a 64x64 f32 tile into LDS as swizzled bf16
__device__ __forceinline__ void stage_tile_f32(const float* __restrict__ g,
                                               int gstride, unsigned short* lds, int tid)
{
    #pragma unroll
    for (int c = tid; c < 512; c += 256) {
        const int r = c >> 3, s = c & 7;
        const float4* src = (const float4*)(g + (size_t)r * gstride + s * 8);
        const float4 a = src[0], b = src[1];
        short8 f;
        f[0] = (short)f2bf(a.x); f[1] = (short)f2bf(a.y);
        f[2] = (short)f2bf(a.z); f[3] = (short)f2bf(a.w);
        f[4] = (short)f2bf(b.x); f[5] = (short)f2bf(b.y);
        f[6] = (short)f2bf(b.z); f[7] = (short)f2bf(b.w);
        char* dst = (char*)lds + r * 128 + ((s * 16) ^ ((r & 7) << 4));
        *reinterpret_cast<short8*>(dst) = f;
    }
}

// read one MFMA A/B fragment octet (8 bf16) from a swizzled 64x64 tile
__device__ __forceinline__ short8 frag_read(const unsigned short* lds, int row, int oct)
{
    const char* src = (const char*)lds + row * 128 + ((oct * 16) ^ ((row & 7) << 4));
    return *reinterpret_cast<const short8*>(src);
}

// ---------------- Kernel 1: q/k/v projections via MFMA ----------------
// x viewed as [NB*S*NH][64] rows (row m = token*8 + head); y = x @ W.T + b
__global__ __launch_bounds__(256) void qkv_mfma(
    const float* __restrict__ x,
    const float* __restrict__ Wq, const float* __restrict__ bq,
    const float* __restrict__ Wk, const float* __restrict__ bk,
    const float* __restrict__ Wv, const float* __restrict__ bv,
    unsigned short* __restrict__ qg, unsigned short* __restrict__ kg,
    unsigned short* __restrict__ vg)
{
    __shared__ unsigned short w_lds[3][64 * 64];

    const int tid  = threadIdx.x;
    const int lane = tid & 63;
    const int w    = tid >> 6;
    const int rowg = lane & 15;
    const int og   = lane >> 4;

    stage_tile_f32(Wq, 64, w_lds[0], tid);
    stage_tile_f32(Wk, 64, w_lds[1], tid);
    stage_tile_f32(Wv, 64, w_lds[2], tid);

    float bias[3][4];
    #pragma unroll
    for (int t = 0; t < 4; ++t) {
        bias[0][t] = bq[16 * t + rowg];
        bias[1][t] = bk[16 * t + rowg];
        bias[2][t] = bv[16 * t + rowg];
    }

    const int m0 = blockIdx.x * 64 + 16 * w;   // stripe base row
    const float* xr = x + (size_t)(m0 + rowg) * 64;
    const float4 a0 = *(const float4*)(xr + og * 8);
    const float4 a1 = *(const float4*)(xr + og * 8 + 4);
    const float4 a2 = *(const float4*)(xr + 32 + og * 8);
    const float4 a3 = *(const float4*)(xr + 32 + og * 8 + 4);
    short8 af0, af1;
    af0[0] = (short)f2bf(a0.x); af0[1] = (short)f2bf(a0.y);
    af0[2] = (short)f2bf(a0.z); af0[3] = (short)f2bf(a0.w);
    af0[4] = (short)f2bf(a1.x); af0[5] = (short)f2bf(a1.y);
    af0[6] = (short)f2bf(a1.z); af0[7] = (short)f2bf(a1.w);
    af1[0] = (short)f2bf(a2.x); af1[1] = (short)f2bf(a2.y);
    af1[2] = (short)f2bf(a2.z); af1[3] = (short)f2bf(a2.w);
    af1[4] = (short)f2bf(a3.x); af1[5] = (short)f2bf(a3.y);
    af1[6] = (short)f2bf(a3.z); af1[7] = (short)f2bf(a3.w);

    __syncthreads();

    f32x4 acc[3][4];
    #pragma unroll
    for (int m = 0; m < 3; ++m)
        #pragma unroll
        for (int t = 0; t < 4; ++t) {
            const float b = bias[m][t];
            acc[m][t] = (f32x4){b, b, b, b};
        }

    #pragma unroll
    for (int m = 0; m < 3; ++m)
        #pragma unroll
        for (int t = 0; t < 4; ++t) {
            acc[m][t] = mfma16(af0, frag_read(w_lds[m], 16 * t + rowg, og),     acc[m][t]);
            acc[m][t] = mfma16(af1, frag_read(w_lds[m], 16 * t + rowg, og + 4), acc[m][t]);
        }

    unsigned short* outp[3] = {qg, kg, vg};
    #pragma unroll
    for (int m = 0; m < 3; ++m)
        #pragma unroll
        for (int r = 0; r < 4; ++r) {
            const int mr = (blockIdx.x * 64 + 16 * w) + og * 4 + r;
            const int tk = mr >> 3, h = mr & 7;
            const int n = tk >> 11, s = tk & 2047;
            const size_t rowb = (((size_t)(n * NH + h)) * S_LEN + s) * 64;
            #pragma unroll
            for (int t = 0; t < 4; ++t)
                outp[m][rowb + 16 * t + rowg] = (unsigned short)(unsigned short)f2bf(acc[m][t][r]);
        }
}

// ---------------- Kernel 1b: transpose V -> vT [nh][64][S] ----------------
__global__ __launch_bounds__(256) void transpose_v(
    const unsigned short* __restrict__ v, unsigned short* __restrict__ vt)
{
    __shared__ unsigned short t_lds[64][72];
    const int bid = blockIdx.x;
    const int st = bid % (S_LEN / 64);
    const int nh = bid / (S_LEN / 64);
    const unsigned short* vp = v + ((size_t)nh * S_LEN + st * 64) * DH;
    unsigned short* vtp = vt + (size_t)nh * DH * S_LEN + st * 64;
    const int tid = threadIdx.x;
    #pragma unroll
    for (int c = tid; c < 512; c += 256) {
        const int r = c >> 3, s = c & 7;
        short8 xv = *reinterpret_cast<const short8*>(vp + r * DH + s * 8);
        #pragma unroll
        for (int i = 0; i < 8; ++i) t_lds[s * 8 + i][r] = (unsigned short)xv[i];
    }
    __syncthreads();
    #pragma unroll
    for (int c = tid; c < 512; c += 256) {
        const int d = c >> 3, s = c & 7;
        short8 y;
        #pragma unroll
        for (int i = 0; i < 8; ++i) y[i] = (short)t_lds[d][s * 8 + i];
        *reinterpret_cast<short8*>(vtp + (size_t)d * S_LEN + s * 8) = y;
    }
}

// ---------------- Kernel 1c: Ehat bf16, reversed rows ----------------
__global__ __launch_bounds__(256) void prep_e(
    const float* __restrict__ E, unsigned short* __restrict__ eb)
{
    const int i = blockIdx.x * 256 + threadIdx.x;
    if (i >= S_LEN * DH) return;
    const int dlt = i >> 6, d = i & 63;
    eb[i] = f2bf(E[(size_t)(S_LEN - 1 - dlt) * DH + d]);
}

// ---------------- Kernel 2: fused MFMA attention ----------------
__global__ __launch_bounds__(256) void attn_mfma(
    const unsigned short* __restrict__ qg,
    const unsigned short* __restrict__ kg,
    const unsigned short* __restrict__ vtg,
    const unsigned short* __restrict__ eg,
    unsigned short* __restrict__ z)
{
    __shared__ unsigned short k_lds[64 * 64];
    __shared__ unsigned short vT_lds[64 * 64];
    __shared__ unsigned short e_lds[64 * 64];
    __shared__ unsigned short p_lds[2][64 * 64];

    constexpr float SM_SCALE = 0.04419417382415922f; // 1/sqrt(512)
    constexpr float UNI = 1.0f / 2048.0f;

    const int nqt = S_LEN / 64;
    const int bid = blockIdx.x;
    const int qt = bid % nqt;
    const int nh = bid / nqt;            // n*NH + h
    const int q0 = qt * 64;
    const size_t base = (size_t)nh * S_LEN * DH;
    const unsigned short* qp = qg + base;
    const unsigned short* kp = kg + base;
    const unsigned short* vp = vtg + base;   // [64][S]

    const int tid  = threadIdx.x;
    const int lane = tid & 63;
    const int w    = tid >> 6;
    const int rowg = lane & 15;
    const int og   = lane >> 4;

    short8 qa0, qa1;
    {
        const unsigned short* qr = qp + (size_t)(q0 + 16 * w + rowg) * DH + og * 8;
        qa0 = *reinterpret_cast<const short8*>(qr);
        qa1 = *reinterpret_cast<const short8*>(qr + 32);
    }

    const f32x4 zero4 = {0.f, 0.f, 0.f, 0.f};
    f32x4 accS[4], accR[4];
    #pragma unroll
    for (int t = 0; t < 4; ++t) { accS[t] = zero4; accR[t] = zero4; }
    float denom[4] = {0.f, 0.f, 0.f, 0.f};
    const int qrow0 = q0 + 16 * w + og * 4;   // C-layout row for reg 0

    // ================= Phase A: softmax part (k > q) =================
    for (int k0 = q0; k0 < S_LEN; k0 += 64) {
        __syncthreads();
        stage_tile(kp + (size_t)k0 * DH, DH, k_lds, tid);
        stage_tile(vp + k0, S_LEN, vT_lds, tid);
        __syncthreads();

        f32x4 P[4];
        #pragma unroll
        for (int t = 0; t < 4; ++t) {
            f32x4 c = zero4;
            c = mfma16(qa0, frag_read(k_lds, 16 * t + rowg, og),     c);
            c = mfma16(qa1, frag_read(k_lds, 16 * t + rowg, og + 4), c);
            P[t] = c;
        }

        float rsum[4] = {0.f, 0.f, 0.f, 0.f};
        #pragma unroll
        for (int t = 0; t < 4; ++t) {
            const int kcol = k0 + 16 * t + rowg;
            #pragma unroll
            for (int r = 0; r < 4; ++r) {
                const int qrow = qrow0 + r;
                float wv = 0.f;
                if (kcol > qrow && qrow != S_LEN - 1)
                    wv = __expf(P[t][r] * SM_SCALE);
                rsum[r] += wv;
                const int prow = 16 * w + og * 4 + r;
                const int pcol = 16 * t + rowg;
                char* dst = (char*)p_lds[0] + prow * 128 + ((pcol * 2) ^ ((prow & 7) << 4));
                *reinterpret_cast<unsigned short*>(dst) = f2bf(wv);
            }
        }
        #pragma unroll
        for (int r = 0; r < 4; ++r) {
            float vv = rsum[r];
            vv += __shfl_xor(vv, 1, 16);
            vv += __shfl_xor(vv, 2, 16);
            vv += __shfl_xor(vv, 4, 16);
            vv += __shfl_xor(vv, 8, 16);
            denom[r] += vv;
        }

        const short8 pa0 = frag_read(p_lds[0], 16 * w + rowg, og);
        const short8 pa1 = frag_read(p_lds[0], 16 * w + rowg, og + 4);
        #pragma unroll
        for (int t = 0; t < 4; ++t) {
            accS[t] = mfma16(pa0, frag_read(vT_lds, 16 * t + rowg, og),     accS[t]);
            accS[t] = mfma16(pa1, frag_read(vT_lds, 16 * t + rowg, og + 4), accS[t]);
        }
    }

    // zero this wave's stripe of p_lds[0] (phase B j=0 needs kk>qq == 0)
    {
        const short8 z8 = {0, 0, 0, 0, 0, 0, 0, 0};
        #pragma unroll
        for (int c2 = lane; c2 < 128; c2 += 64) {
            const int r = 16 * w + (c2 >> 3), s = c2 & 7;
            *reinterpret_cast<short8*>((char*)p_lds[0] + r * 128 + s * 16) = z8;
        }
    }

    // ============ Phase B: relative-position part (k <= q) ============
    const int jmax = q0 / 64;
    for (int j = 0; j <= jmax; ++j) {
        const int k0 = q0 - 64 * j;
        __syncthreads();
        stage_tile(eg + (size_t)(64 * j) * DH, DH, e_lds, tid);
        stage_tile(vp + k0, S_LEN, vT_lds, tid);
        __syncthreads();

        f32x4 G[4];
        #pragma unroll
        for (int t = 0; t < 4; ++t) {
            f32x4 c = zero4;
            c = mfma16(qa0, frag_read(e_lds, 16 * t + rowg, og),     c);
            c = mfma16(qa1, frag_read(e_lds, 16 * t + rowg, og + 4), c);
            G[t] = c;
        }

        unsigned short* pc = p_lds[j & 1];
        unsigned short* pn = p_lds[(j + 1) & 1];
        #pragma unroll
        for (int t = 0; t < 4; ++t) {
            const int c = 16 * t + rowg;          // delta offset within block
            #pragma unroll
            for (int r = 0; r < 4; ++r) {
                const int qq = 16 * w + og * 4 + r;
                const int qrow = q0 + qq;
                float val = G[t][r];
                if (qrow == S_LEN - 1) val += UNI;   // uniform-softmax row fold-in
                const unsigned short bv = f2bf(val);
                if (c <= qq) {
                    const int pcol = qq - c;
                    char* dst = (char*)pc + qq * 128 + ((pcol * 2) ^ ((qq & 7) << 4));
                    *reinterpret_cast<unsigned short*>(dst) = bv;
                } else if (j < jmax) {
                    const int pcol = qq - c + 64;
                    char* dst = (char*)pn + qq * 128 + ((pcol * 2) ^ ((qq & 7) << 4));
                    *reinterpret_cast<unsigned short*>(dst) = bv;
                }
            }
        }

        const short8 pa0 = frag_read(pc, 16 * w + rowg, og);
        const short8 pa1 = frag_read(pc, 16 * w + rowg, og + 4);
        #pragma unroll
        for (int t = 0; t < 4; ++t) {
            accR[t] = mfma16(pa0, frag_read(vT_lds, 16 * t + rowg, og),     accR[t]);
            accR[t] = mfma16(pa1, frag_read(vT_lds, 16 * t + rowg, og + 4), accR[t]);
        }
    }

    // ================= epilogue: z = accS/denom + accR (bf16) =================
    const int n = nh / NH, h = nh % NH;
    #pragma unroll
    for (int r = 0; r < 4; ++r) {
        const int qrow = qrow0 + r;
        const float inv = (qrow == S_LEN - 1) ? 0.f : 1.f / denom[r];
        #pragma unroll
        for (int t = 0; t < 4; ++t) {
            const float zv = accS[t][r] * inv + accR[t][r];
            z[((size_t)n * S_LEN + qrow) * EMB + h * DH + 16 * t + rowg] = f2bf(zv);
        }
    }
}

// ---------------- Kernel 3: output projection via MFMA ----------------
// out[m][o] = sum_e z[m][e] * Wo[o][e] + bo[o]; M=8192, N=K=512
__global__ __launch_bounds__(256) void outproj_mfma(
    const unsigned short* __restrict__ z,   // [8192][512] bf16
    const float* __restrict__ Wo, const float* __restrict__ bo,
    float* __restrict__ out)
{
    __shared__ unsigned short wo_lds[64 * 64];

    const int tid  = threadIdx.x;
    const int lane = tid & 63;
    const int w    = tid >> 6;
    const int rowg = lane & 15;
    const int og   = lane >> 4;

    const int nob = EMB / 64;                  // 8
    const int mb = blockIdx.x / nob;           // 0..127
    const int ob = blockIdx.x % nob;
    const int m0 = mb * 64 + 16 * w;
    const int o0 = ob * 64;

    f32x4 acc[4];
    #pragma unroll
    for (int t = 0; t < 4; ++t) {
        const float b = bo[o0 + 16 * t + rowg];
        acc[t] = (f32x4){b, b, b, b};
    }

    for (int k0 = 0; k0 < EMB; k0 += 64) {
        __syncthreads();
        stage_tile_f32(Wo + (size_t)o0 * EMB + k0, EMB, wo_lds, tid);
        __syncthreads();
        const unsigned short* zr = z + (size_t)(m0 + rowg) * EMB + k0;
        const short8 af0 = *reinterpret_cast<const short8*>(zr + og * 8);
        const short8 af1 = *reinterpret_cast<const short8*>(zr + 32 + og * 8);
        #pragma unroll
        for (int t = 0; t < 4; ++t) {
            acc[t] = mfma16(af0, frag_read(wo_lds, 16 * t + rowg, og),     acc[t]);
            acc[t] = mfma16(af1, frag_read(wo_lds, 16 * t + rowg, og + 4), acc[t]);
        }
    }

    #pragma unroll
    for (int r = 0; r < 4; ++r) {
        const size_t rowb = (size_t)(m0 + og * 4 + r) * EMB + o0;
        #pragma unroll
        for (int t = 0; t < 4; ++t)
            out[rowb + 16 * t + rowg] = acc[t][r];
    }
}

// ---------------- launch ----------------
extern "C" void kernel_launch(void* const* d_in, const int* in_sizes, int n_in,
                              void* d_out, int out_size, void* d_ws, size_t ws_size,
                              hipStream_t stream) {
    const float* x  = (const float*)d_in[0];
    const float* Wq = (const float*)d_in[1];
    const float* bq = (const float*)d_in[2];
    const float* Wk = (const float*)d_in[3];
    const float* bk = (const float*)d_in[4];
    const float* Wv = (const float*)d_in[5];
    const float* bv = (const float*)d_in[6];
    const float* E  = (const float*)d_in[7];
    const float* Wo = (const float*)d_in[8];
    const float* bo = (const float*)d_in[9];
    float* out = (float*)d_out;

    const size_t per = (size_t)NB * NH * S_LEN * DH;       // 4M elements
    unsigned short* qb  = (unsigned short*)d_ws;
    unsigned short* kb  = qb  + per;
    unsigned short* vb  = kb  + per;
    unsigned short* vtb = vb  + per;
    unsigned short* eb  = vtb + per;
    unsigned short* zb  = eb + (size_t)S_LEN * DH;

    qkv_mfma<<<(NB * S_LEN * NH) / 64, 256, 0, stream>>>(x, Wq, bq, Wk, bk, Wv, bv,
                                                         qb, kb, vb);
    transpose_v<<<NB * NH * (S_LEN / 64), 256, 0, stream>>>(vb, vtb);
    prep_e<<<(S_LEN * DH + 255) / 256, 256, 0, stream>>>(E, eb);
    attn_mfma<<<NB * NH * (S_LEN / 64), 256, 0, stream>>>(qb, kb, vtb, eb, zb);
    outproj_mfma<<<(NB * S_LEN / 64) * (EMB / 64), 256, 0, stream>>>(zb, Wo, bo, out);
}

// Round 4
// 137.905 us; speedup vs baseline: 11.8035x; 1.1739x over previous
//
#include <hip/hip_runtime.h>
#include <hip/hip_bf16.h>

#define S_LEN 2048
#define EMB   512
#define NH    8
#define DH    64
#define NB    4

typedef float f32x4  __attribute__((ext_vector_type(4)));
typedef short short8 __attribute__((ext_vector_type(8)));
typedef short short4v __attribute__((ext_vector_type(4)));

__device__ __forceinline__ unsigned short f2bf(float f) {
    unsigned u = __builtin_bit_cast(unsigned, f);
    u += 0x7fffu + ((u >> 16) & 1u);
    return (unsigned short)(u >> 16);
}

__device__ __forceinline__ f32x4 mfma16(short8 a, short8 b, f32x4 c) {
    return __builtin_amdgcn_mfma_f32_16x16x32_bf16(a, b, c, 0, 0, 0);
}

__device__ __forceinline__ float dot4(const float4 a, const float4 b) {
    return a.x*b.x + a.y*b.y + a.z*b.z + a.w*b.w;
}

// read one MFMA A/B fragment octet (8 bf16) from a swizzled 64x64 tile
__device__ __forceinline__ short8 frag_read(const unsigned short* lds, int row, int oct)
{
    const char* src = (const char*)lds + row * 128 + ((oct * 16) ^ ((row & 7) << 4));
    return *reinterpret_cast<const short8*>(src);
}

// two 8B reads from swizzled row -> one short8 (permuted V fragment)
__device__ __forceinline__ short8 vb_pair(const unsigned short* lds, int row, int ba, int bb)
{
    const char* base = (const char*)lds + row * 128;
    const int sw = (row & 7) << 4;
    short4v lo = *reinterpret_cast<const short4v*>(base + (ba ^ sw));
    short4v hi = *reinterpret_cast<const short4v*>(base + (bb ^ sw));
    return __builtin_shufflevector(lo, hi, 0, 1, 2, 3, 4, 5, 6, 7);
}

// stage a 64x64 f32 tile into LDS as swizzled bf16 (for weight tiles)
__device__ __forceinline__ void stage_tile_f32(const float* __restrict__ g,
                                               int gstride, unsigned short* lds, int tid)
{
    #pragma unroll
    for (int c = tid; c < 512; c += 256) {
        const int r = c >> 3, s = c & 7;
        const float4* src = (const float4*)(g + (size_t)r * gstride + s * 8);
        const float4 a = src[0], b = src[1];
        short8 f;
        f[0] = (short)f2bf(a.x); f[1] = (short)f2bf(a.y);
        f[2] = (short)f2bf(a.z); f[3] = (short)f2bf(a.w);
        f[4] = (short)f2bf(b.x); f[5] = (short)f2bf(b.y);
        f[6] = (short)f2bf(b.z); f[7] = (short)f2bf(b.w);
        char* dst = (char*)lds + r * 128 + ((s * 16) ^ ((r & 7) << 4));
        *reinterpret_cast<short8*>(dst) = f;
    }
}

// ---------------- Kernel 1: q/k/v projections via MFMA ----------------
__global__ __launch_bounds__(256) void qkv_mfma(
    const float* __restrict__ x,
    const float* __restrict__ Wq, const float* __restrict__ bq,
    const float* __restrict__ Wk, const float* __restrict__ bk,
    const float* __restrict__ Wv, const float* __restrict__ bv,
    unsigned short* __restrict__ qg, unsigned short* __restrict__ kg,
    unsigned short* __restrict__ vg)
{
    __shared__ unsigned short w_lds[3][64 * 64];

    const int tid  = threadIdx.x;
    const int lane = tid & 63;
    const int w    = tid >> 6;
    const int rowg = lane & 15;
    const int og   = lane >> 4;

    stage_tile_f32(Wq, 64, w_lds[0], tid);
    stage_tile_f32(Wk, 64, w_lds[1], tid);
    stage_tile_f32(Wv, 64, w_lds[2], tid);

    float bias[3][4];
    #pragma unroll
    for (int t = 0; t < 4; ++t) {
        bias[0][t] = bq[16 * t + rowg];
        bias[1][t] = bk[16 * t + rowg];
        bias[2][t] = bv[16 * t + rowg];
    }

    const int m0 = blockIdx.x * 64 + 16 * w;
    const float* xr = x + (size_t)(m0 + rowg) * 64;
    const float4 a0 = *(const float4*)(xr + og * 8);
    const float4 a1 = *(const float4*)(xr + og * 8 + 4);
    const float4 a2 = *(const float4*)(xr + 32 + og * 8);
    const float4 a3 = *(const float4*)(xr + 32 + og * 8 + 4);
    short8 af0, af1;
    af0[0] = (short)f2bf(a0.x); af0[1] = (short)f2bf(a0.y);
    af0[2] = (short)f2bf(a0.z); af0[3] = (short)f2bf(a0.w);
    af0[4] = (short)f2bf(a1.x); af0[5] = (short)f2bf(a1.y);
    af0[6] = (short)f2bf(a1.z); af0[7] = (short)f2bf(a1.w);
    af1[0] = (short)f2bf(a2.x); af1[1] = (short)f2bf(a2.y);
    af1[2] = (short)f2bf(a2.z); af1[3] = (short)f2bf(a2.w);
    af1[4] = (short)f2bf(a3.x); af1[5] = (short)f2bf(a3.y);
    af1[6] = (short)f2bf(a3.z); af1[7] = (short)f2bf(a3.w);

    __syncthreads();

    f32x4 acc[3][4];
    #pragma unroll
    for (int m = 0; m < 3; ++m)
        #pragma unroll
        for (int t = 0; t < 4; ++t) {
            const float b = bias[m][t];
            acc[m][t] = (f32x4){b, b, b, b};
        }

    #pragma unroll
    for (int m = 0; m < 3; ++m)
        #pragma unroll
        for (int t = 0; t < 4; ++t) {
            acc[m][t] = mfma16(af0, frag_read(w_lds[m], 16 * t + rowg, og),     acc[m][t]);
            acc[m][t] = mfma16(af1, frag_read(w_lds[m], 16 * t + rowg, og + 4), acc[m][t]);
        }

    unsigned short* outp[3] = {qg, kg, vg};
    #pragma unroll
    for (int m = 0; m < 3; ++m)
        #pragma unroll
        for (int r = 0; r < 4; ++r) {
            const int mr = (blockIdx.x * 64 + 16 * w) + og * 4 + r;
            const int tk = mr >> 3, h = mr & 7;
            const int n = tk >> 11, s = tk & 2047;
            const size_t rowb = (((size_t)(n * NH + h)) * S_LEN + s) * 64;
            #pragma unroll
            for (int t = 0; t < 4; ++t)
                outp[m][rowb + 16 * t + rowg] = f2bf(acc[m][t][r]);
        }
}

// ---------------- Kernel 1b: transpose V -> vT [nh][64][S] ----------------
__global__ __launch_bounds__(256) void transpose_v(
    const unsigned short* __restrict__ v, unsigned short* __restrict__ vt)
{
    __shared__ unsigned short t_lds[64][72];
    const int bid = blockIdx.x;
    const int st = bid % (S_LEN / 64);
    const int nh = bid / (S_LEN / 64);
    const unsigned short* vp = v + ((size_t)nh * S_LEN + st * 64) * DH;
    unsigned short* vtp = vt + (size_t)nh * DH * S_LEN + st * 64;
    const int tid = threadIdx.x;
    #pragma unroll
    for (int c = tid; c < 512; c += 256) {
        const int r = c >> 3, s = c & 7;
        short8 xv = *reinterpret_cast<const short8*>(vp + r * DH + s * 8);
        #pragma unroll
        for (int i = 0; i < 8; ++i) t_lds[s * 8 + i][r] = (unsigned short)xv[i];
    }
    __syncthreads();
    #pragma unroll
    for (int c = tid; c < 512; c += 256) {
        const int d = c >> 3, s = c & 7;
        short8 y;
        #pragma unroll
        for (int i = 0; i < 8; ++i) y[i] = (short)t_lds[d][s * 8 + i];
        *reinterpret_cast<short8*>(vtp + (size_t)d * S_LEN + s * 8) = y;
    }
}

// ---------------- Kernel 1c: Ehat bf16, reversed rows ----------------
__global__ __launch_bounds__(256) void prep_e(
    const float* __restrict__ E, unsigned short* __restrict__ eb)
{
    const int i = blockIdx.x * 256 + threadIdx.x;
    if (i >= S_LEN * DH) return;
    const int dlt = i >> 6, d = i & 63;
    eb[i] = f2bf(E[(size_t)(S_LEN - 1 - dlt) * DH + d]);
}

// ---------------- Kernel 2: fused MFMA attention ----------------
// Phase A (k>q, softmax): swapped QK^T -> P in registers, permuted-V PV.
// Phase B (k<=q, skew): rolling Q.Ehat matmul with p_lds scatter.
__global__ __launch_bounds__(256) void attn_mfma(
    const unsigned short* __restrict__ qg,
    const unsigned short* __restrict__ kg,
    const unsigned short* __restrict__ vtg,
    const unsigned short* __restrict__ eg,
    unsigned short* __restrict__ z)
{
    __shared__ unsigned short kbuf[2][64 * 64];   // K tiles (phase A) / E tiles (phase B)
    __shared__ unsigned short vbuf[2][64 * 64];   // vT tiles
    __shared__ unsigned short p_lds[2][64 * 64];  // phase-B skew weights

    constexpr float SM_SCALE = 0.04419417382415922f; // 1/sqrt(512)
    constexpr float UNI = 1.0f / 2048.0f;

    const int nqt = S_LEN / 64;
    const int bid = blockIdx.x;
    const int qt = bid % nqt;
    const int nh = bid / nqt;
    const int q0 = qt * 64;
    const size_t base = (size_t)nh * S_LEN * DH;
    const unsigned short* qp = qg + base;
    const unsigned short* kp = kg + base;
    const unsigned short* vp = vtg + base;   // [64][S]

    const int tid  = threadIdx.x;
    const int lane = tid & 63;
    const int w    = tid >> 6;
    const int rowg = lane & 15;
    const int og   = lane >> 4;

    // staging chunk constants (chunks c0=tid, c1=tid+256 of 512 short8 chunks)
    const int r0 = tid >> 3,         s0 = tid & 7;
    const int r1 = (tid + 256) >> 3;
    const int ldsoff0 = r0 * 128 + ((s0 * 16) ^ ((r0 & 7) << 4));
    const int ldsoff1 = r1 * 128 + ((s0 * 16) ^ ((r1 & 7) << 4));
    const int ksrc0 = r0 * 64 + s0 * 8,     ksrc1 = r1 * 64 + s0 * 8;
    const int vsrc0 = r0 * S_LEN + s0 * 8,  vsrc1 = r1 * S_LEN + s0 * 8;

    short8 kr0, kr1, vr0, vr1;   // staging registers

    // Q fragments (A-layout == B-layout): lane&15 = q-row-in-stripe
    short8 qa0, qa1;
    {
        const unsigned short* qr = qp + (size_t)(q0 + 16 * w + rowg) * DH + og * 8;
        qa0 = *reinterpret_cast<const short8*>(qr);
        qa1 = *reinterpret_cast<const short8*>(qr + 32);
    }

    const f32x4 zero4 = {0.f, 0.f, 0.f, 0.f};
    f32x4 accS[4], accR[4];
    #pragma unroll
    for (int t = 0; t < 4; ++t) { accS[t] = zero4; accR[t] = zero4; }
    float dsum = 0.f;

    // ================= Phase A =================
    // prologue: stage diagonal tile into buf0
    kr0 = *(const short8*)(kp + (size_t)q0 * 64 + ksrc0);
    kr1 = *(const short8*)(kp + (size_t)q0 * 64 + ksrc1);
    vr0 = *(const short8*)(vp + q0 + vsrc0);
    vr1 = *(const short8*)(vp + q0 + vsrc1);
    *(short8*)((char*)kbuf[0] + ldsoff0) = kr0;
    *(short8*)((char*)kbuf[0] + ldsoff1) = kr1;
    *(short8*)((char*)vbuf[0] + ldsoff0) = vr0;
    *(short8*)((char*)vbuf[0] + ldsoff1) = vr1;
    __syncthreads();

    int cur = 0;
    for (int k0 = q0; k0 < S_LEN; k0 += 64) {
        const bool pf = (k0 + 64 < S_LEN);
        if (pf) {
            const unsigned short* kb = kp + (size_t)(k0 + 64) * 64;
            const unsigned short* vb = vp + (k0 + 64);
            kr0 = *(const short8*)(kb + ksrc0);
            kr1 = *(const short8*)(kb + ksrc1);
            vr0 = *(const short8*)(vb + vsrc0);
            vr1 = *(const short8*)(vb + vsrc1);
        }

        const unsigned short* klds = kbuf[cur];
        const unsigned short* vlds = vbuf[cur];

        // swapped QK^T: C'[t] rows = k (16t + og*4 + r), col = q (lane&15)
        f32x4 C[4];
        #pragma unroll
        for (int t = 0; t < 4; ++t) {
            f32x4 c = zero4;
            c = mfma16(frag_read(klds, 16 * t + rowg, og),     qa0, c);
            c = mfma16(frag_read(klds, 16 * t + rowg, og + 4), qa1, c);
            C[t] = c;
        }

        // softmax weights in-register
        unsigned short pw[16];
        float rsum = 0.f;
        const bool diag = (k0 == q0);
        #pragma unroll
        for (int t = 0; t < 4; ++t) {
            #pragma unroll
            for (int r = 0; r < 4; ++r) {
                float wv;
                if (diag && t < w) {
                    wv = 0.f;
                } else if (diag && t == w) {
                    wv = (og * 4 + r > rowg) ? __expf(C[t][r] * SM_SCALE) : 0.f;
                } else {
                    wv = __expf(C[t][r] * SM_SCALE);
                }
                rsum += wv;
                pw[t * 4 + r] = f2bf(wv);
            }
        }
        dsum += rsum;

        short8 pa0, pa1;
        #pragma unroll
        for (int i = 0; i < 8; ++i) { pa0[i] = (short)pw[i]; pa1[i] = (short)pw[8 + i]; }

        // PV with permuted-column V fragments
        #pragma unroll
        for (int tt = 0; tt < 4; ++tt) {
            const int vrow = 16 * tt + rowg;
            const short8 vb0 = vb_pair(vlds, vrow, og * 8,      32 + og * 8);
            const short8 vb1 = vb_pair(vlds, vrow, 64 + og * 8, 96 + og * 8);
            accS[tt] = mfma16(pa0, vb0, accS[tt]);
            accS[tt] = mfma16(pa1, vb1, accS[tt]);
        }

        if (pf) {
            unsigned short* kn = kbuf[cur ^ 1];
            unsigned short* vn = vbuf[cur ^ 1];
            *(short8*)((char*)kn + ldsoff0) = kr0;
            *(short8*)((char*)kn + ldsoff1) = kr1;
            *(short8*)((char*)vn + ldsoff0) = vr0;
            *(short8*)((char*)vn + ldsoff1) = vr1;
        }
        __syncthreads();
        cur ^= 1;
    }

    // ================= Phase B =================
    const int jmax = q0 / 64;
    // prologue: stage E(0) + vT(q0) into buf0
    kr0 = *(const short8*)(eg + ksrc0);
    kr1 = *(const short8*)(eg + ksrc1);
    vr0 = *(const short8*)(vp + q0 + vsrc0);
    vr1 = *(const short8*)(vp + q0 + vsrc1);
    // zero own stripe of p_lds[0] while loads are in flight
    {
        const short8 z8 = {0, 0, 0, 0, 0, 0, 0, 0};
        #pragma unroll
        for (int c2 = lane; c2 < 128; c2 += 64) {
            const int r = 16 * w + (c2 >> 3), s = c2 & 7;
            *reinterpret_cast<short8*>((char*)p_lds[0] + r * 128 + s * 16) = z8;
        }
    }
    *(short8*)((char*)kbuf[0] + ldsoff0) = kr0;
    *(short8*)((char*)kbuf[0] + ldsoff1) = kr1;
    *(short8*)((char*)vbuf[0] + ldsoff0) = vr0;
    *(short8*)((char*)vbuf[0] + ldsoff1) = vr1;
    __syncthreads();

    cur = 0;
    for (int j = 0; j <= jmax; ++j) {
        const bool pf = (j < jmax);
        if (pf) {
            const unsigned short* ebn = eg + (size_t)(j + 1) * 4096;
            const unsigned short* vbn = vp + (q0 - 64 * (j + 1));
            kr0 = *(const short8*)(ebn + ksrc0);
            kr1 = *(const short8*)(ebn + ksrc1);
            vr0 = *(const short8*)(vbn + vsrc0);
            vr1 = *(const short8*)(vbn + vsrc1);
        }

        const unsigned short* elds = kbuf[cur];
        const unsigned short* vlds = vbuf[cur];

        f32x4 G[4];
        #pragma unroll
        for (int t = 0; t < 4; ++t) {
            f32x4 c = zero4;
            c = mfma16(qa0, frag_read(elds, 16 * t + rowg, og),     c);
            c = mfma16(qa1, frag_read(elds, 16 * t + rowg, og + 4), c);
            G[t] = c;
        }

        unsigned short* pc = p_lds[j & 1];
        unsigned short* pn = p_lds[(j + 1) & 1];
        #pragma unroll
        for (int t = 0; t < 4; ++t) {
            const int c = 16 * t + rowg;
            #pragma unroll
            for (int r = 0; r < 4; ++r) {
                const int qq = 16 * w + og * 4 + r;
                const int qrow = q0 + qq;
                float val = G[t][r];
                if (qrow == S_LEN - 1) val += UNI;
                const unsigned short bv = f2bf(val);
                if (c <= qq) {
                    const int pcol = qq - c;
                    char* dst = (char*)pc + qq * 128 + ((pcol * 2) ^ ((qq & 7) << 4));
                    *reinterpret_cast<unsigned short*>(dst) = bv;
                } else if (j < jmax) {
                    const int pcol = qq - c + 64;
                    char* dst = (char*)pn + qq * 128 + ((pcol * 2) ^ ((qq & 7) << 4));
                    *reinterpret_cast<unsigned short*>(dst) = bv;
                }
            }
        }

        const short8 pb0 = frag_read(pc, 16 * w + rowg, og);
        const short8 pb1 = frag_read(pc, 16 * w + rowg, og + 4);
        #pragma unroll
        for (int tt = 0; tt < 4; ++tt) {
            accR[tt] = mfma16(pb0, frag_read(vlds, 16 * tt + rowg, og),     accR[tt]);
            accR[tt] = mfma16(pb1, frag_read(vlds, 16 * tt + rowg, og + 4), accR[tt]);
        }

        if (pf) {
            unsigned short* kn = kbuf[cur ^ 1];
            unsigned short* vn = vbuf[cur ^ 1];
            *(short8*)((char*)kn + ldsoff0) = kr0;
            *(short8*)((char*)kn + ldsoff1) = kr1;
            *(short8*)((char*)vn + ldsoff0) = vr0;
            *(short8*)((char*)vn + ldsoff1) = vr1;
        }
        __syncthreads();
        cur ^= 1;
    }

    // ================= epilogue =================
    dsum += __shfl_xor(dsum, 16, 64);
    dsum += __shfl_xor(dsum, 32, 64);

    const int n = nh / NH, h = nh % NH;
    const int qrow0 = q0 + 16 * w + og * 4;
    #pragma unroll
    for (int r = 0; r < 4; ++r) {
        const int qrow = qrow0 + r;
        const float dn = __shfl(dsum, og * 4 + r, 64);
        const float inv = (qrow == S_LEN - 1) ? 0.f : 1.f / dn;
        #pragma unroll
        for (int t = 0; t < 4; ++t) {
            const float zv = accS[t][r] * inv + accR[t][r];
            z[((size_t)n * S_LEN + qrow) * EMB + h * DH + 16 * t + rowg] = f2bf(zv);
        }
    }
}

// ---------------- Kernel 3: output projection via MFMA ----------------
__global__ __launch_bounds__(256) void outproj_mfma(
    const unsigned short* __restrict__ z,
    const float* __restrict__ Wo, const float* __restrict__ bo,
    float* __restrict__ out)
{
    __shared__ unsigned short wo_lds[64 * 64];

    const int tid  = threadIdx.x;
    const int lane = tid & 63;
    const int w    = tid >> 6;
    const int rowg = lane & 15;
    const int og   = lane >> 4;

    const int nob = EMB / 64;
    const int mb = blockIdx.x / nob;
    const int ob = blockIdx.x % nob;
    const int m0 = mb * 64 + 16 * w;
    const int o0 = ob * 64;

    f32x4 acc[4];
    #pragma unroll
    for (int t = 0; t < 4; ++t) {
        const float b = bo[o0 + 16 * t + rowg];
        acc[t] = (f32x4){b, b, b, b};
    }

    for (int k0 = 0; k0 < EMB; k0 += 64) {
        __syncthreads();
        stage_tile_f32(Wo + (size_t)o0 * EMB + k0, EMB, wo_lds, tid);
        __syncthreads();
        const unsigned short* zr = z + (size_t)(m0 + rowg) * EMB + k0;
        const short8 af0 = *reinterpret_cast<const short8*>(zr + og * 8);
        const short8 af1 = *reinterpret_cast<const short8*>(zr + 32 + og * 8);
        #pragma unroll
        for (int t = 0; t < 4; ++t) {
            acc[t] = mfma16(af0, frag_read(wo_lds, 16 * t + rowg, og),     acc[t]);
            acc[t] = mfma16(af1, frag_read(wo_lds, 16 * t + rowg, og + 4), acc[t]);
        }
    }

    #pragma unroll
    for (int r = 0; r < 4; ++r) {
        const size_t rowb = (size_t)(m0 + og * 4 + r) * EMB + o0;
        #pragma unroll
        for (int t = 0; t < 4; ++t)
            out[rowb + 16 * t + rowg] = acc[t][r];
    }
}

// ---------------- launch ----------------
extern "C" void kernel_launch(void* const* d_in, const int* in_sizes, int n_in,
                              void* d_out, int out_size, void* d_ws, size_t ws_size,
                              hipStream_t stream) {
    const float* x  = (const float*)d_in[0];
    const float* Wq = (const float*)d_in[1];
    const float* bq = (const float*)d_in[2];
    const float* Wk = (const float*)d_in[3];
    const float* bk = (const float*)d_in[4];
    const float* Wv = (const float*)d_in[5];
    const float* bv = (const float*)d_in[6];
    const float* E  = (const float*)d_in[7];
    const float* Wo = (const float*)d_in[8];
    const float* bo = (const float*)d_in[9];
    float* out = (float*)d_out;

    const size_t per = (size_t)NB * NH * S_LEN * DH;
    unsigned short* qb  = (unsigned short*)d_ws;
    unsigned short* kb  = qb  + per;
    unsigned short* vb  = kb  + per;
    unsigned short* vtb = vb  + per;
    unsigned short* eb  = vtb + per;
    unsigned short* zb  = eb + (size_t)S_LEN * DH;

    qkv_mfma<<<(NB * S_LEN * NH) / 64, 256, 0, stream>>>(x, Wq, bq, Wk, bk, Wv, bv,
                                                         qb, kb, vb);
    transpose_v<<<NB * NH * (S_LEN / 64), 256, 0, stream>>>(vb, vtb);
    prep_e<<<(S_LEN * DH + 255) / 256, 256, 0, stream>>>(E, eb);
    attn_mfma<<<NB * NH * (S_LEN / 64), 256, 0, stream>>>(qb, kb, vtb, eb, zb);
    outproj_mfma<<<(NB * S_LEN / 64) * (EMB / 64), 256, 0, stream>>>(zb, Wo, bo, out);
}

// Round 6
// 121.565 us; speedup vs baseline: 13.3901x; 1.1344x over previous
//
#include <hip/hip_runtime.h>
#include <hip/hip_bf16.h>

#define S_LEN 2048
#define EMB   512
#define NH    8
#define DH    64
#define NB    4

typedef float f32x4  __attribute__((ext_vector_type(4)));
typedef short short8 __attribute__((ext_vector_type(8)));

__device__ __forceinline__ unsigned short f2bf_rn(float f) {
    return __builtin_bit_cast(unsigned short, __float2bfloat16(f));
}

__device__ __forceinline__ f32x4 mfma16(short8 a, short8 b, f32x4 c) {
    return __builtin_amdgcn_mfma_f32_16x16x32_bf16(a, b, c, 0, 0, 0);
}

// read one MFMA A/B fragment octet (8 bf16) from a swizzled 64x64 tile
__device__ __forceinline__ short8 frag_read(const unsigned short* lds, int row, int oct)
{
    const char* src = (const char*)lds + row * 128 + ((oct * 16) ^ ((row & 7) << 4));
    return *reinterpret_cast<const short8*>(src);
}

// inverse of the vT column permutation pi:
// pi(p) = (p&32) + ((p>>3)&3)*4 + (p&3) + ((p&4)?16:0)
__device__ __forceinline__ int pinv(int k) {
    return (k & 32) + ((k >> 2) & 3) * 8 + (k & 3) + ((k & 16) >> 2);
}

// stage a 64x64 f32 tile into LDS as swizzled bf16 (weight tiles)
__device__ __forceinline__ void stage_tile_f32(const float* __restrict__ g,
                                               int gstride, unsigned short* lds, int tid)
{
    #pragma unroll
    for (int c = tid; c < 512; c += 256) {
        const int r = c >> 3, s = c & 7;
        const float4* src = (const float4*)(g + (size_t)r * gstride + s * 8);
        const float4 a = src[0], b = src[1];
        short8 f;
        f[0] = (short)f2bf_rn(a.x); f[1] = (short)f2bf_rn(a.y);
        f[2] = (short)f2bf_rn(a.z); f[3] = (short)f2bf_rn(a.w);
        f[4] = (short)f2bf_rn(b.x); f[5] = (short)f2bf_rn(b.y);
        f[6] = (short)f2bf_rn(b.z); f[7] = (short)f2bf_rn(b.w);
        char* dst = (char*)lds + r * 128 + ((s * 16) ^ ((r & 7) << 4));
        *reinterpret_cast<short8*>(dst) = f;
    }
}

// softmax 16 scores -> bf16 A-fragments + running denom partial
__device__ __forceinline__ void softmax_pack(const f32x4 C[4], bool diag, int w, int og,
                                             int rowg, float& dsum, short8& pa0, short8& pa1)
{
    constexpr float SM_SCALE = 0.04419417382415922f; // 1/sqrt(512)
    float rsum = 0.f;
    unsigned short pw[16];
    if (!diag) {
        #pragma unroll
        for (int t = 0; t < 4; ++t)
            #pragma unroll
            for (int r = 0; r < 4; ++r) {
                const float wv = __expf(C[t][r] * SM_SCALE);
                rsum += wv;
                pw[t * 4 + r] = f2bf_rn(wv);
            }
    } else {
        #pragma unroll
        for (int t = 0; t < 4; ++t)
            #pragma unroll
            for (int r = 0; r < 4; ++r) {
                const bool keep = (t > w) || (t == w && (og * 4 + r) > rowg);
                const float wv = keep ? __expf(C[t][r] * SM_SCALE) : 0.f;
                rsum += wv;
                pw[t * 4 + r] = f2bf_rn(wv);
            }
    }
    dsum += rsum;
    #pragma unroll
    for (int i = 0; i < 8; ++i) { pa0[i] = (short)pw[i]; pa1[i] = (short)pw[8 + i]; }
}

// ---------------- Kernel 1: q/k/v projections via MFMA ----------------
__global__ __launch_bounds__(256) void qkv_mfma(
    const float* __restrict__ x,
    const float* __restrict__ Wq, const float* __restrict__ bq,
    const float* __restrict__ Wk, const float* __restrict__ bk,
    const float* __restrict__ Wv, const float* __restrict__ bv,
    unsigned short* __restrict__ qg, unsigned short* __restrict__ kg,
    unsigned short* __restrict__ vg)
{
    __shared__ unsigned short w_lds[3][64 * 64];

    const int tid  = threadIdx.x;
    const int lane = tid & 63;
    const int w    = tid >> 6;
    const int rowg = lane & 15;
    const int og   = lane >> 4;

    stage_tile_f32(Wq, 64, w_lds[0], tid);
    stage_tile_f32(Wk, 64, w_lds[1], tid);
    stage_tile_f32(Wv, 64, w_lds[2], tid);

    float bias[3][4];
    #pragma unroll
    for (int t = 0; t < 4; ++t) {
        bias[0][t] = bq[16 * t + rowg];
        bias[1][t] = bk[16 * t + rowg];
        bias[2][t] = bv[16 * t + rowg];
    }

    const int m0 = blockIdx.x * 64 + 16 * w;
    const float* xr = x + (size_t)(m0 + rowg) * 64;
    const float4 a0 = *(const float4*)(xr + og * 8);
    const float4 a1 = *(const float4*)(xr + og * 8 + 4);
    const float4 a2 = *(const float4*)(xr + 32 + og * 8);
    const float4 a3 = *(const float4*)(xr + 32 + og * 8 + 4);
    short8 af0, af1;
    af0[0] = (short)f2bf_rn(a0.x); af0[1] = (short)f2bf_rn(a0.y);
    af0[2] = (short)f2bf_rn(a0.z); af0[3] = (short)f2bf_rn(a0.w);
    af0[4] = (short)f2bf_rn(a1.x); af0[5] = (short)f2bf_rn(a1.y);
    af0[6] = (short)f2bf_rn(a1.z); af0[7] = (short)f2bf_rn(a1.w);
    af1[0] = (short)f2bf_rn(a2.x); af1[1] = (short)f2bf_rn(a2.y);
    af1[2] = (short)f2bf_rn(a2.z); af1[3] = (short)f2bf_rn(a2.w);
    af1[4] = (short)f2bf_rn(a3.x); af1[5] = (short)f2bf_rn(a3.y);
    af1[6] = (short)f2bf_rn(a3.z); af1[7] = (short)f2bf_rn(a3.w);

    __syncthreads();

    f32x4 acc[3][4];
    #pragma unroll
    for (int m = 0; m < 3; ++m)
        #pragma unroll
        for (int t = 0; t < 4; ++t) {
            const float b = bias[m][t];
            acc[m][t] = (f32x4){b, b, b, b};
        }

    #pragma unroll
    for (int m = 0; m < 3; ++m)
        #pragma unroll
        for (int t = 0; t < 4; ++t) {
            acc[m][t] = mfma16(af0, frag_read(w_lds[m], 16 * t + rowg, og),     acc[m][t]);
            acc[m][t] = mfma16(af1, frag_read(w_lds[m], 16 * t + rowg, og + 4), acc[m][t]);
        }

    unsigned short* outp[3] = {qg, kg, vg};
    #pragma unroll
    for (int m = 0; m < 3; ++m)
        #pragma unroll
        for (int r = 0; r < 4; ++r) {
            const int mr = (blockIdx.x * 64 + 16 * w) + og * 4 + r;
            const int tk = mr >> 3, h = mr & 7;
            const int n = tk >> 11, s = tk & 2047;
            const size_t rowb = (((size_t)(n * NH + h)) * S_LEN + s) * 64;
            #pragma unroll
            for (int t = 0; t < 4; ++t)
                outp[m][rowb + 16 * t + rowg] = f2bf_rn(acc[m][t][r]);
        }
}

// ------- Kernel 1b: transpose V -> vT [nh][64][S], columns pi-permuted per 64 -------
__global__ __launch_bounds__(256) void transpose_v(
    const unsigned short* __restrict__ v, unsigned short* __restrict__ vt)
{
    __shared__ unsigned short t_lds[64][72];
    const int bid = blockIdx.x;
    const int st = bid % (S_LEN / 64);
    const int nh = bid / (S_LEN / 64);
    const unsigned short* vp = v + ((size_t)nh * S_LEN + st * 64) * DH;
    unsigned short* vtp = vt + (size_t)nh * DH * S_LEN + st * 64;
    const int tid = threadIdx.x;
    #pragma unroll
    for (int c = tid; c < 512; c += 256) {
        const int r = c >> 3, s = c & 7;
        short8 xv = *reinterpret_cast<const short8*>(vp + r * DH + s * 8);
        #pragma unroll
        for (int i = 0; i < 8; ++i) t_lds[s * 8 + i][r] = (unsigned short)xv[i];
    }
    __syncthreads();
    #pragma unroll
    for (int c = tid; c < 512; c += 256) {
        const int d = c >> 3, sc = c & 7;
        const int cb = ((sc & 4) << 3) + (sc & 3) * 4;   // pi base
        short8 y;
        #pragma unroll
        for (int i = 0; i < 8; ++i)
            y[i] = (short)t_lds[d][cb + (i & 3) + ((i & 4) << 2)];
        *reinterpret_cast<short8*>(vtp + (size_t)d * S_LEN + sc * 8) = y;
    }
}

// ---------------- Kernel 1c: Ehat bf16, reversed rows ----------------
__global__ __launch_bounds__(256) void prep_e(
    const float* __restrict__ E, unsigned short* __restrict__ eb)
{
    const int i = blockIdx.x * 256 + threadIdx.x;
    if (i >= S_LEN * DH) return;
    const int dlt = i >> 6, d = i & 63;
    eb[i] = f2bf_rn(E[(size_t)(S_LEN - 1 - dlt) * DH + d]);
}

// ---------------- Kernel 2: fused MFMA attention (64-row Q tile) ----------------
__global__ __launch_bounds__(256) void attn_mfma(
    const unsigned short* __restrict__ qg,
    const unsigned short* __restrict__ kg,
    const unsigned short* __restrict__ vtg,
    const unsigned short* __restrict__ eg,
    unsigned short* __restrict__ z)
{
    __shared__ unsigned short kbuf[2][64 * 64];   // K (phase A) / E (phase B)
    __shared__ unsigned short vbuf[2][64 * 64];   // vT tiles (pi-permuted cols)
    __shared__ unsigned short p_lds[2][64 * 64];  // phase-B skew weights

    constexpr float UNI = 1.0f / 2048.0f;

    const int nqt = S_LEN / 64;                   // 32
    const int bid = blockIdx.x;
    const int qt  = (nqt - 1) - (bid >> 5);       // heavy blocks first
    const int nh  = bid & 31;
    const int q0  = qt * 64;
    const size_t base = (size_t)nh * S_LEN * DH;
    const unsigned short* qp = qg + base;
    const unsigned short* kp = kg + base;
    const unsigned short* vp = vtg + base;        // [64][S], cols permuted per 64

    const int tid  = threadIdx.x;
    const int lane = tid & 63;
    const int w    = tid >> 6;
    const int rowg = lane & 15;
    const int og   = lane >> 4;

    const int r0 = tid >> 3,  s0 = tid & 7;
    const int r1 = r0 + 32;
    const int ldsoff0 = r0 * 128 + ((s0 * 16) ^ ((r0 & 7) << 4));
    const int ldsoff1 = r1 * 128 + ((s0 * 16) ^ ((r1 & 7) << 4));
    const int ksrc0 = r0 * 64 + s0 * 8,    ksrc1 = r1 * 64 + s0 * 8;
    const int vsrc0 = r0 * S_LEN + s0 * 8, vsrc1 = r1 * S_LEN + s0 * 8;

    short8 kr0, kr1, vr0, vr1;

    short8 qa0, qa1;
    {
        const unsigned short* qr = qp + (size_t)(q0 + 16 * w + rowg) * DH + og * 8;
        qa0 = *reinterpret_cast<const short8*>(qr);
        qa1 = *reinterpret_cast<const short8*>(qr + 32);
    }

    const f32x4 zero4 = {0.f, 0.f, 0.f, 0.f};
    f32x4 accS[4], accR[4];
    #pragma unroll
    for (int t = 0; t < 4; ++t) { accS[t] = zero4; accR[t] = zero4; }
    float dsum = 0.f;

    // ================= Phase A (k > q, softmax) =================
    kr0 = *(const short8*)(kp + (size_t)q0 * 64 + ksrc0);
    kr1 = *(const short8*)(kp + (size_t)q0 * 64 + ksrc1);
    vr0 = *(const short8*)(vp + q0 + vsrc0);
    vr1 = *(const short8*)(vp + q0 + vsrc1);
    *(short8*)((char*)kbuf[0] + ldsoff0) = kr0;
    *(short8*)((char*)kbuf[0] + ldsoff1) = kr1;
    *(short8*)((char*)vbuf[0] + ldsoff0) = vr0;
    *(short8*)((char*)vbuf[0] + ldsoff1) = vr1;
    __syncthreads();

    int cur = 0;
    for (int k0 = q0; k0 < S_LEN; k0 += 64) {
        const bool pf = (k0 + 64 < S_LEN);
        if (pf) {
            const unsigned short* kb = kp + (size_t)(k0 + 64) * 64;
            const unsigned short* vb = vp + (k0 + 64);
            kr0 = *(const short8*)(kb + ksrc0);
            kr1 = *(const short8*)(kb + ksrc1);
            vr0 = *(const short8*)(vb + vsrc0);
            vr1 = *(const short8*)(vb + vsrc1);
        }
        const unsigned short* klds = kbuf[cur];
        const unsigned short* vlds = vbuf[cur];

        // swapped QK^T: lane owns one q (rowg), 16 k-slots
        f32x4 C[4];
        #pragma unroll
        for (int t = 0; t < 4; ++t) {
            const short8 kf0 = frag_read(klds, 16 * t + rowg, og);
            const short8 kf1 = frag_read(klds, 16 * t + rowg, og + 4);
            C[t] = mfma16(kf1, qa1, mfma16(kf0, qa0, zero4));
        }
        short8 pa0, pa1;
        softmax_pack(C, k0 == q0, w, og, rowg, dsum, pa0, pa1);

        #pragma unroll
        for (int tt = 0; tt < 4; ++tt) {
            const short8 vf0 = frag_read(vlds, 16 * tt + rowg, og);
            const short8 vf1 = frag_read(vlds, 16 * tt + rowg, og + 4);
            accS[tt] = mfma16(pa1, vf1, mfma16(pa0, vf0, accS[tt]));
        }

        if (pf) {
            *(short8*)((char*)kbuf[cur ^ 1] + ldsoff0) = kr0;
            *(short8*)((char*)kbuf[cur ^ 1] + ldsoff1) = kr1;
            *(short8*)((char*)vbuf[cur ^ 1] + ldsoff0) = vr0;
            *(short8*)((char*)vbuf[cur ^ 1] + ldsoff1) = vr1;
        }
        __syncthreads();
        cur ^= 1;
    }

    // ================= Phase B (k <= q, skew) =================
    const int jmax = q0 >> 6;
    // zero own stripe of p_lds[0]
    {
        const short8 z8 = {0, 0, 0, 0, 0, 0, 0, 0};
        #pragma unroll
        for (int c2 = 0; c2 < 2; ++c2) {
            const int cc = lane + 64 * c2;
            const int r = 16 * w + (cc >> 3), sc = cc & 7;
            *reinterpret_cast<short8*>((char*)p_lds[0] + r * 128 + sc * 16) = z8;
        }
    }
    kr0 = *(const short8*)(eg + ksrc0);
    kr1 = *(const short8*)(eg + ksrc1);
    vr0 = *(const short8*)(vp + q0 + vsrc0);
    vr1 = *(const short8*)(vp + q0 + vsrc1);
    *(short8*)((char*)kbuf[0] + ldsoff0) = kr0;
    *(short8*)((char*)kbuf[0] + ldsoff1) = kr1;
    *(short8*)((char*)vbuf[0] + ldsoff0) = vr0;
    *(short8*)((char*)vbuf[0] + ldsoff1) = vr1;
    __syncthreads();

    int cur2 = 0;
    for (int j = 0; j <= jmax; ++j) {
        const bool pf = (j < jmax);
        if (pf) {
            const unsigned short* ebn = eg + (size_t)(j + 1) * 4096;
            const unsigned short* vbn = vp + (q0 - 64 * (j + 1));
            kr0 = *(const short8*)(ebn + ksrc0);
            kr1 = *(const short8*)(ebn + ksrc1);
            vr0 = *(const short8*)(vbn + vsrc0);
            vr1 = *(const short8*)(vbn + vsrc1);
        }
        const unsigned short* elds = kbuf[cur2];
        const unsigned short* vlds = vbuf[cur2];

        f32x4 G[4];
        #pragma unroll
        for (int t = 0; t < 4; ++t)
            G[t] = mfma16(qa1, frag_read(elds, 16 * t + rowg, og + 4),
                   mfma16(qa0, frag_read(elds, 16 * t + rowg, og), zero4));

        unsigned short* pc = p_lds[j & 1];
        unsigned short* pn = p_lds[(j + 1) & 1];
        #pragma unroll
        for (int t = 0; t < 4; ++t) {
            const int c = 16 * t + rowg;
            #pragma unroll
            for (int r = 0; r < 4; ++r) {
                const int qq = 16 * w + og * 4 + r;
                float val = G[t][r];
                if (q0 + qq == S_LEN - 1) val += UNI;   // uniform-softmax row fold-in
                const unsigned short bv = f2bf_rn(val);
                const int swz = (qq & 7) << 4;
                if (c <= qq) {
                    const int p = pinv(qq - c);
                    *(unsigned short*)((char*)pc + qq * 128 + ((p * 2) ^ swz)) = bv;
                } else if (pf) {
                    const int p = pinv(qq - c + 64);
                    *(unsigned short*)((char*)pn + qq * 128 + ((p * 2) ^ swz)) = bv;
                }
            }
        }

        const short8 pb0 = frag_read(pc, 16 * w + rowg, og);
        const short8 pb1 = frag_read(pc, 16 * w + rowg, og + 4);
        #pragma unroll
        for (int tt = 0; tt < 4; ++tt) {
            const short8 vf0 = frag_read(vlds, 16 * tt + rowg, og);
            const short8 vf1 = frag_read(vlds, 16 * tt + rowg, og + 4);
            accR[tt] = mfma16(pb1, vf1, mfma16(pb0, vf0, accR[tt]));
        }

        if (pf) {
            *(short8*)((char*)kbuf[cur2 ^ 1] + ldsoff0) = kr0;
            *(short8*)((char*)kbuf[cur2 ^ 1] + ldsoff1) = kr1;
            *(short8*)((char*)vbuf[cur2 ^ 1] + ldsoff0) = vr0;
            *(short8*)((char*)vbuf[cur2 ^ 1] + ldsoff1) = vr1;
        }
        __syncthreads();
        cur2 ^= 1;
    }

    // ================= epilogue =================
    dsum += __shfl_xor(dsum, 16);
    dsum += __shfl_xor(dsum, 32);

    const int n = nh >> 3, h = nh & 7;
    const int qrow0 = q0 + 16 * w + og * 4;
    #pragma unroll
    for (int r = 0; r < 4; ++r) {
        const int qrow = qrow0 + r;
        const float dn = __shfl(dsum, og * 4 + r);
        const float inv = (qrow == S_LEN - 1) ? 0.f : 1.f / dn;
        #pragma unroll
        for (int t = 0; t < 4; ++t) {
            const float zv = accS[t][r] * inv + accR[t][r];
            z[((size_t)n * S_LEN + qrow) * EMB + h * DH + 16 * t + rowg] = f2bf_rn(zv);
        }
    }
}

// ---------------- Kernel 3: output projection via MFMA ----------------
__global__ __launch_bounds__(256) void outproj_mfma(
    const unsigned short* __restrict__ z,
    const float* __restrict__ Wo, const float* __restrict__ bo,
    float* __restrict__ out)
{
    __shared__ unsigned short wo_lds[64 * 64];

    const int tid  = threadIdx.x;
    const int lane = tid & 63;
    const int w    = tid >> 6;
    const int rowg = lane & 15;
    const int og   = lane >> 4;

    const int nob = EMB / 64;
    const int mb = blockIdx.x / nob;
    const int ob = blockIdx.x % nob;
    const int m0 = mb * 64 + 16 * w;
    const int o0 = ob * 64;

    f32x4 acc[4];
    #pragma unroll
    for (int t = 0; t < 4; ++t) {
        const float b = bo[o0 + 16 * t + rowg];
        acc[t] = (f32x4){b, b, b, b};
    }

    for (int k0 = 0; k0 < EMB; k0 += 64) {
        __syncthreads();
        stage_tile_f32(Wo + (size_t)o0 * EMB + k0, EMB, wo_lds, tid);
        __syncthreads();
        const unsigned short* zr = z + (size_t)(m0 + rowg) * EMB + k0;
        const short8 af0 = *reinterpret_cast<const short8*>(zr + og * 8);
        const short8 af1 = *reinterpret_cast<const short8*>(zr + 32 + og * 8);
        #pragma unroll
        for (int t = 0; t < 4; ++t) {
            acc[t] = mfma16(af0, frag_read(wo_lds, 16 * t + rowg, og),     acc[t]);
            acc[t] = mfma16(af1, frag_read(wo_lds, 16 * t + rowg, og + 4), acc[t]);
        }
    }

    #pragma unroll
    for (int r = 0; r < 4; ++r) {
        const size_t rowb = (size_t)(m0 + og * 4 + r) * EMB + o0;
        #pragma unroll
        for (int t = 0; t < 4; ++t)
            out[rowb + 16 * t + rowg] = acc[t][r];
    }
}

// ---------------- launch ----------------
extern "C" void kernel_launch(void* const* d_in, const int* in_sizes, int n_in,
                              void* d_out, int out_size, void* d_ws, size_t ws_size,
                              hipStream_t stream) {
    const float* x  = (const float*)d_in[0];
    const float* Wq = (const float*)d_in[1];
    const float* bq = (const float*)d_in[2];
    const float* Wk = (const float*)d_in[3];
    const float* bk = (const float*)d_in[4];
    const float* Wv = (const float*)d_in[5];
    const float* bv = (const float*)d_in[6];
    const float* E  = (const float*)d_in[7];
    const float* Wo = (const float*)d_in[8];
    const float* bo = (const float*)d_in[9];
    float* out = (float*)d_out;

    const size_t per = (size_t)NB * NH * S_LEN * DH;
    unsigned short* qb  = (unsigned short*)d_ws;
    unsigned short* kb  = qb  + per;
    unsigned short* vb  = kb  + per;
    unsigned short* vtb = vb  + per;
    unsigned short* eb  = vtb + per;
    unsigned short* zb  = eb + (size_t)S_LEN * DH;

    qkv_mfma<<<(NB * S_LEN * NH) / 64, 256, 0, stream>>>(x, Wq, bq, Wk, bk, Wv, bv,
                                                         qb, kb, vb);
    transpose_v<<<NB * NH * (S_LEN / 64), 256, 0, stream>>>(vb, vtb);
    prep_e<<<(S_LEN * DH + 255) / 256, 256, 0, stream>>>(E, eb);
    attn_mfma<<<NB * NH * (S_LEN / 64), 256, 0, stream>>>(qb, kb, vtb, eb, zb);
    outproj_mfma<<<(NB * S_LEN / 64) * (EMB / 64), 256, 0, stream>>>(zb, Wo, bo, out);
}